// Round 5
// baseline (101.066 us; speedup 1.0000x reference)
//
#include <hip/hip_runtime.h>
#include <hip/hip_bf16.h>

// Problem constants
#define D_IN 1024
#define D_EMB 512
#define HIDDEN 256
#define NUM_CLASSES 64
#define N_SUPPORT 4096
#define N_QUERY 8192

typedef __bf16 bf16x8 __attribute__((ext_vector_type(8)));
typedef __bf16 bf16x4 __attribute__((ext_vector_type(4)));
typedef float f32x4 __attribute__((ext_vector_type(4)));

#define GLOAD_LDS16(g, l)                                                          \
  __builtin_amdgcn_global_load_lds(                                                \
      (const __attribute__((address_space(1))) unsigned int*)(g),                  \
      (__attribute__((address_space(3))) unsigned int*)(l), 16, 0, 0)

// ---------------------------------------------------------------------------
// Fused transpose of both weight matrices -> bf16 [cols][rows]:
//   blocks [0,512):  W_e [1024][512]  -> WeT [512][1024]
//   blocks [512,640): W1[:512][256]   -> WqT [256][512]
// ---------------------------------------------------------------------------
__global__ void transpose_weights(const float* __restrict__ W_e,
                                  const float* __restrict__ W1,
                                  __bf16* __restrict__ WeT,
                                  __bf16* __restrict__ WqT) {
  __shared__ float tile[32][33];
  const float* in;
  __bf16* out;
  int bx, by, rows, cols;
  int b = blockIdx.x;
  if (b < 512) {
    in = W_e; out = WeT; rows = D_IN; cols = D_EMB;
    bx = (b & 15) * 32; by = (b >> 4) * 32;
  } else {
    b -= 512;
    in = W1; out = WqT; rows = D_EMB; cols = HIDDEN;  // W1[:512] only
    bx = (b & 7) * 32; by = (b >> 3) * 32;
  }
  int tx = threadIdx.x;
  int ty = threadIdx.y;
#pragma unroll
  for (int i = ty; i < 32; i += 8)
    tile[i][tx] = in[(long)(by + i) * cols + bx + tx];
  __syncthreads();
#pragma unroll
  for (int i = ty; i < 32; i += 8)
    out[(long)(bx + i) * rows + by + tx] = (__bf16)tile[tx][i];
}

// ---------------------------------------------------------------------------
// Embedding GEMM, 2-phase double-buffered, fused fp32->bf16 A conversion:
//   emb[12288][512] = relu( [support;query](fp32) @ WeT^T + b_e ) -> bf16
// BM=128, BN=64, BK=32. grid 768 (96 m-tiles x 8 n-tiles), XCD-swizzled so
// all 8 n-tiles of one m-tile share an XCD (A tile L2-resident).
// Per iter: issue A-loads(t+1)+B-gld(t+1) -> compute(t) -> cvt+write A(t+1)
// -> one barrier. Compiler inserts counted vmcnt on the av use.
// ---------------------------------------------------------------------------
__global__ __launch_bounds__(256, 2) void gemm_emb(
    const float* __restrict__ support, const float* __restrict__ query,
    const __bf16* __restrict__ BT, const float* __restrict__ bias,
    __bf16* __restrict__ C) {
  constexpr int BM = 128, BN = 64, BK = 32;
  constexpr int N = D_EMB, K = D_IN;
  constexpr int LDA_S = 40;   // padded bf16 stride (80 B rows)
  constexpr int NT = K / BK;  // 32
  constexpr int MR = 4, NR = 2;

  __shared__ __align__(16) __bf16 As[2][BM * LDA_S];  // 2 x 10240 B
  __shared__ __align__(16) __bf16 Bs[2][BN * BK];     // 2 x 4096 B

  const int tid = threadIdx.x;
  const int wave = tid >> 6, lane = tid & 63;
  const int wr = wave >> 1, wc = wave & 1;
  const int l16 = lane & 15, half = lane >> 4;

  // XCD swizzle: s = (m&7) | (n<<3) | ((m>>3)<<6); XCD(s)=s%8=m%8
  const int s = blockIdx.x;
  const int m_t = (s & 7) + (s >> 6) * 8;   // 0..95
  const int n_t = (s >> 3) & 7;             // 0..7
  const int m0 = m_t * BM, n0 = n_t * BN;

  // block never straddles the support/query boundary (4096 % 128 == 0)
  const float* Abase = (m0 < N_SUPPORT)
                           ? support + (long)m0 * K
                           : query + (long)(m0 - N_SUPPORT) * K;

  // A staging: 512 chunks of 8 fp32; thread owns chunks {tid, tid+256}
  const int ar0 = tid >> 2, ar1 = (tid + 256) >> 2;
  const int ac = tid & 3;  // same for both chunks
  const int brow = tid >> 2, bkc = tid & 3;

  float4 av[2][2];

  f32x4 acc[MR][NR];
#pragma unroll
  for (int m = 0; m < MR; ++m)
#pragma unroll
    for (int n = 0; n < NR; ++n) acc[m][n] = (f32x4)0.0f;

#define LOAD_A(t)                                                         \
  {                                                                       \
    const float* p0 = Abase + (long)ar0 * K + (t) * BK + ac * 8;          \
    const float* p1 = Abase + (long)ar1 * K + (t) * BK + ac * 8;          \
    av[0][0] = *(const float4*)(p0);                                      \
    av[0][1] = *(const float4*)(p0 + 4);                                  \
    av[1][0] = *(const float4*)(p1);                                      \
    av[1][1] = *(const float4*)(p1 + 4);                                  \
  }

#define WRITE_A(buf)                                                      \
  {                                                                       \
    bf16x8 o0, o1;                                                        \
    o0[0] = (__bf16)av[0][0].x; o0[1] = (__bf16)av[0][0].y;               \
    o0[2] = (__bf16)av[0][0].z; o0[3] = (__bf16)av[0][0].w;               \
    o0[4] = (__bf16)av[0][1].x; o0[5] = (__bf16)av[0][1].y;               \
    o0[6] = (__bf16)av[0][1].z; o0[7] = (__bf16)av[0][1].w;               \
    o1[0] = (__bf16)av[1][0].x; o1[1] = (__bf16)av[1][0].y;               \
    o1[2] = (__bf16)av[1][0].z; o1[3] = (__bf16)av[1][0].w;               \
    o1[4] = (__bf16)av[1][1].x; o1[5] = (__bf16)av[1][1].y;               \
    o1[6] = (__bf16)av[1][1].z; o1[7] = (__bf16)av[1][1].w;               \
    *(bf16x8*)(&As[buf][ar0 * LDA_S + ac * 8]) = o0;                      \
    *(bf16x8*)(&As[buf][ar1 * LDA_S + ac * 8]) = o1;                      \
  }

#define GLD_B(t, buf)                                                     \
  GLOAD_LDS16(BT + (long)(n0 + brow) * K + (t) * BK + bkc * 8,            \
              &Bs[buf][tid * 8]);

#define COMPUTE(buf)                                                      \
  {                                                                       \
    bf16x8 a[MR], b[NR];                                                  \
    _Pragma("unroll") for (int m = 0; m < MR; ++m)                        \
        a[m] = *(const bf16x8*)(&As[buf][(wr * 64 + m * 16 + l16) *       \
                                             LDA_S + half * 8]);          \
    _Pragma("unroll") for (int n = 0; n < NR; ++n)                        \
        b[n] = *(const bf16x8*)(&Bs[buf][(wc * 32 + n * 16 + l16) * BK +  \
                                         half * 8]);                      \
    _Pragma("unroll") for (int m = 0; m < MR; ++m)                        \
        _Pragma("unroll") for (int n = 0; n < NR; ++n)                    \
            acc[m][n] = __builtin_amdgcn_mfma_f32_16x16x32_bf16(          \
                a[m], b[n], acc[m][n], 0, 0, 0);                          \
  }

  // prologue: stage tile 0 into buf 0
  LOAD_A(0);
  GLD_B(0, 0);
  WRITE_A(0);
  __syncthreads();

  int cur = 0;
  for (int t = 0; t < NT - 1; ++t) {
    LOAD_A(t + 1);        // fp32 -> regs (consumed after MFMA phase)
    GLD_B(t + 1, cur ^ 1);  // async -> LDS[nxt]
    COMPUTE(cur);
    WRITE_A(cur ^ 1);     // counted vmcnt wait on av, then ds_write_b128
    __syncthreads();
    cur ^= 1;
  }
  COMPUTE(cur);

#undef LOAD_A
#undef WRITE_A
#undef GLD_B
#undef COMPUTE

  // epilogue: C/D layout col = lane&15, row = (lane>>4)*4 + j
#pragma unroll
  for (int m = 0; m < MR; ++m)
#pragma unroll
    for (int n = 0; n < NR; ++n)
#pragma unroll
      for (int j = 0; j < 4; ++j) {
        int row = m0 + wr * 64 + m * 16 + half * 4 + j;
        int col = n0 + wc * 32 + n * 16 + l16;
        float v = fmaxf(acc[m][n][j] + bias[col], 0.0f);
        C[(long)row * N + col] = (__bf16)v;
      }
}

// ---------------------------------------------------------------------------
// qp GEMM, 2-phase double-buffered (both operands via global_load_lds):
//   qp[8192][256] = q_emb(bf16) @ WqT^T + b1   (f32 out)
// BM=128, BN=64, BK=32. grid 256 (64 m-tiles x 4 n-tiles), XCD-swizzled.
// ---------------------------------------------------------------------------
__global__ __launch_bounds__(256, 2) void gemm_qp(
    const __bf16* __restrict__ A, const __bf16* __restrict__ BT,
    const float* __restrict__ bias, float* __restrict__ C) {
  constexpr int BM = 128, BN = 64, BK = 32;
  constexpr int N = HIDDEN, K = D_EMB;
  constexpr int NT = K / BK;  // 16
  constexpr int MR = 4, NR = 2;

  __shared__ __align__(16) __bf16 As[2][BM * BK];  // 2 x 8192 B
  __shared__ __align__(16) __bf16 Bs[2][BN * BK];  // 2 x 4096 B

  const int tid = threadIdx.x;
  const int wave = tid >> 6, lane = tid & 63;
  const int wr = wave >> 1, wc = wave & 1;
  const int l16 = lane & 15, half = lane >> 4;

  // XCD swizzle: s = (m&7) | (n<<3) | ((m>>3)<<5)
  const int s = blockIdx.x;
  const int m_t = (s & 7) + (s >> 5) * 8;  // 0..63
  const int n_t = (s >> 3) & 3;            // 0..3
  const int m0 = m_t * BM, n0 = n_t * BN;

  const int arow0 = tid >> 2, arow1 = (tid + 256) >> 2;
  const int akc = tid & 3;
  const int brow = tid >> 2, bkc = tid & 3;

  f32x4 acc[MR][NR];
#pragma unroll
  for (int m = 0; m < MR; ++m)
#pragma unroll
    for (int n = 0; n < NR; ++n) acc[m][n] = (f32x4)0.0f;

#define STAGE(t, buf)                                                     \
  {                                                                       \
    GLOAD_LDS16(A + (long)(m0 + arow0) * K + (t) * BK + akc * 8,          \
                &As[buf][tid * 8]);                                       \
    GLOAD_LDS16(A + (long)(m0 + arow1) * K + (t) * BK + akc * 8,          \
                &As[buf][(tid + 256) * 8]);                               \
    GLOAD_LDS16(BT + (long)(n0 + brow) * K + (t) * BK + bkc * 8,          \
                &Bs[buf][tid * 8]);                                       \
  }

#define COMPUTE(buf)                                                      \
  {                                                                       \
    bf16x8 a[MR], b[NR];                                                  \
    _Pragma("unroll") for (int m = 0; m < MR; ++m)                        \
        a[m] = *(const bf16x8*)(&As[buf][(wr * 64 + m * 16 + l16) * BK +  \
                                         half * 8]);                      \
    _Pragma("unroll") for (int n = 0; n < NR; ++n)                        \
        b[n] = *(const bf16x8*)(&Bs[buf][(wc * 32 + n * 16 + l16) * BK +  \
                                         half * 8]);                      \
    _Pragma("unroll") for (int m = 0; m < MR; ++m)                        \
        _Pragma("unroll") for (int n = 0; n < NR; ++n)                    \
            acc[m][n] = __builtin_amdgcn_mfma_f32_16x16x32_bf16(          \
                a[m], b[n], acc[m][n], 0, 0, 0);                          \
  }

  STAGE(0, 0);
  __syncthreads();

  int cur = 0;
  for (int t = 0; t < NT - 1; ++t) {
    STAGE(t + 1, cur ^ 1);  // async loads span the compute phase
    COMPUTE(cur);
    __syncthreads();        // drains vmcnt for loads issued pre-compute
    cur ^= 1;
  }
  COMPUTE(cur);

#undef STAGE
#undef COMPUTE

#pragma unroll
  for (int m = 0; m < MR; ++m)
#pragma unroll
    for (int n = 0; n < NR; ++n)
#pragma unroll
      for (int j = 0; j < 4; ++j) {
        int row = m0 + wr * 64 + m * 16 + half * 4 + j;
        int col = n0 + wc * 32 + n * 16 + l16;
        C[(long)row * N + col] = acc[m][n][j] + bias[col];
      }
}

// ---------------------------------------------------------------------------
// class partial sums, no atomics / no zero-init. grid (64 classes, 8 slices).
// ---------------------------------------------------------------------------
__global__ __launch_bounds__(256) void proto_partial(
    const __bf16* __restrict__ s_emb, const int* __restrict__ labels,
    float* __restrict__ sums_part, int* __restrict__ cnt_part) {
  const int c = blockIdx.x;
  const int s = blockIdx.y;  // 0..7
  const int tid = threadIdx.x;
  const int j0 = s * (N_SUPPORT / 8);
  float a0 = 0.0f, a1 = 0.0f;
  int count = 0;
#pragma unroll 4
  for (int j = j0; j < j0 + N_SUPPORT / 8; j += 4) {
    int4 lab4 = *(const int4*)(labels + j);
#pragma unroll
    for (int u = 0; u < 4; ++u) {
      int lab = (u == 0) ? lab4.x : (u == 1) ? lab4.y : (u == 2) ? lab4.z : lab4.w;
      if (lab == c) {
        const __bf16* r = s_emb + (long)(j + u) * D_EMB;
        a0 += (float)r[tid];
        a1 += (float)r[tid + 256];
        ++count;
      }
    }
  }
  float* dst = sums_part + (long)(c * 8 + s) * D_EMB;
  dst[tid] = a0;
  dst[tid + 256] = a1;
  if (tid == 0) cnt_part[c * 8 + s] = count;
}

// ---------------------------------------------------------------------------
// cpb_part[kc][c][n] = sum_{k in chunk kc} means[c][k] * W1[(D_EMB+k)][n]
// grid (64, 4). b1 folded into qp GEMM bias.
// ---------------------------------------------------------------------------
__global__ __launch_bounds__(256) void proto_cpb(
    const float* __restrict__ sums_part, const int* __restrict__ cnt_part,
    const float* __restrict__ W1, float* __restrict__ cpb_part) {
  __shared__ float ls[128];
  const int c = blockIdx.x;
  const int kc = blockIdx.y;
  const int k0 = kc * 128;
  const int tid = threadIdx.x;

  int nc = 0;
#pragma unroll
  for (int s = 0; s < 8; ++s) nc += cnt_part[c * 8 + s];
  float inv = 1.0f / fmaxf((float)nc, 1.0f);

  if (tid < 128) {
    float v = 0.0f;
#pragma unroll
    for (int s = 0; s < 8; ++s)
      v += sums_part[(long)(c * 8 + s) * D_EMB + k0 + tid];
    ls[tid] = v * inv;
  }
  __syncthreads();

  float acc = 0.0f;
#pragma unroll 8
  for (int k = 0; k < 128; ++k)
    acc = fmaf(ls[k], W1[(long)(D_EMB + k0 + k) * HIDDEN + tid], acc);
  cpb_part[((long)kc * NUM_CLASSES + c) * HIDDEN + tid] = acc;
}

__global__ void cpb_reduce(const float* __restrict__ cpb_part,
                           float* __restrict__ cpb) {
  int i = blockIdx.x * 256 + threadIdx.x;  // 16384 threads
  const int n = NUM_CLASSES * HIDDEN;
  cpb[i] = cpb_part[i] + cpb_part[n + i] + cpb_part[2 * n + i] +
           cpb_part[3 * n + i];
}

// ---------------------------------------------------------------------------
// fused score: out[q][c] = sigmoid( sum_k relu(qp[q,k]+cpb[c,k]) * W2[k] + b2 )
// lane = class c; wave handles 8 q-rows; block = 4 waves = 32 q-rows.
// ---------------------------------------------------------------------------
__global__ __launch_bounds__(256) void score_kernel(
    const float* __restrict__ qp, const float* __restrict__ cpb,
    const float* __restrict__ W2, const float* __restrict__ b2,
    float* __restrict__ out) {
  constexpr int CPB_S = 260;  // f32 stride: 1040 B, 16B aligned
  __shared__ __align__(16) float cpb_s[NUM_CLASSES * CPB_S];
  __shared__ __align__(16) float qp_s[32 * HIDDEN];
  __shared__ __align__(16) float w2_s[HIDDEN];

  const int tid = threadIdx.x;
  const int w = tid >> 6;
  const int c = tid & 63;
  const int qb0 = blockIdx.x * 32;

  w2_s[tid] = W2[tid];
  for (int i = tid; i < NUM_CLASSES * HIDDEN; i += 256)
    cpb_s[(i >> 8) * CPB_S + (i & (HIDDEN - 1))] = cpb[i];
  for (int i = tid; i < 32 * HIDDEN; i += 256)
    qp_s[i] = qp[(long)qb0 * HIDDEN + i];
  __syncthreads();

  const float bb = b2[0];
  float acc[8];
#pragma unroll
  for (int q = 0; q < 8; ++q) acc[q] = 0.0f;

  const float* crow = cpb_s + c * CPB_S;
  const float* qbase = qp_s + (w * 8) * HIDDEN;

#pragma unroll 4
  for (int kc = 0; kc < HIDDEN / 4; ++kc) {
    f32x4 cv = *(const f32x4*)(crow + kc * 4);
    f32x4 wv = *(const f32x4*)(w2_s + kc * 4);
#pragma unroll
    for (int q = 0; q < 8; ++q) {
      f32x4 qv = *(const f32x4*)(qbase + q * HIDDEN + kc * 4);
      acc[q] = fmaf(fmaxf(qv[0] + cv[0], 0.0f), wv[0], acc[q]);
      acc[q] = fmaf(fmaxf(qv[1] + cv[1], 0.0f), wv[1], acc[q]);
      acc[q] = fmaf(fmaxf(qv[2] + cv[2], 0.0f), wv[2], acc[q]);
      acc[q] = fmaf(fmaxf(qv[3] + cv[3], 0.0f), wv[3], acc[q]);
    }
  }

#pragma unroll
  for (int q = 0; q < 8; ++q) {
    float x = acc[q] + bb;
    out[(long)(qb0 + w * 8 + q) * NUM_CLASSES + c] = 1.0f / (1.0f + __expf(-x));
  }
}

// ---------------------------------------------------------------------------
extern "C" void kernel_launch(void* const* d_in, const int* in_sizes, int n_in,
                              void* d_out, int out_size, void* d_ws,
                              size_t ws_size, hipStream_t stream) {
  const float* support = (const float*)d_in[0];
  const float* query   = (const float*)d_in[1];
  const int*   labels  = (const int*)d_in[2];
  const float* W_e     = (const float*)d_in[3];
  const float* b_e     = (const float*)d_in[4];
  const float* W1      = (const float*)d_in[5];
  const float* b1      = (const float*)d_in[6];
  const float* W2      = (const float*)d_in[7];
  const float* b2      = (const float*)d_in[8];
  float* out = (float*)d_out;

  char* ws = (char*)d_ws;
  size_t off = 0;
  auto alloc = [&](size_t bytes) {
    void* p = ws + off;
    off = (off + bytes + 255) & ~(size_t)255;
    return p;
  };
  const long NTOT = N_SUPPORT + N_QUERY;  // 12288
  __bf16* WeT = (__bf16*)alloc((size_t)D_EMB * D_IN * 2);
  __bf16* WqT = (__bf16*)alloc((size_t)HIDDEN * D_EMB * 2);
  __bf16* emb = (__bf16*)alloc((size_t)NTOT * D_EMB * 2);
  float*  qp  = (float*)alloc((size_t)N_QUERY * HIDDEN * 4);
  float*  sums_part = (float*)alloc((size_t)NUM_CLASSES * 8 * D_EMB * 4);
  int*    cnt_part  = (int*)alloc((size_t)NUM_CLASSES * 8 * 4);
  float*  cpb_part  = (float*)alloc((size_t)4 * NUM_CLASSES * HIDDEN * 4);
  float*  cpb       = (float*)alloc((size_t)NUM_CLASSES * HIDDEN * 4);

  // both weight transposes in one dispatch
  transpose_weights<<<640, dim3(32, 8), 0, stream>>>(W_e, W1, WeT, WqT);

  // embeddings with fused fp32->bf16 A conversion, 2-phase pipeline
  gemm_emb<<<768, 256, 0, stream>>>(support, query, WeT, b_e, emb);

  // class prototypes: partial sums (no atomics) -> projection parts -> reduce
  proto_partial<<<dim3(NUM_CLASSES, 8), 256, 0, stream>>>(emb, labels, sums_part,
                                                          cnt_part);
  proto_cpb<<<dim3(NUM_CLASSES, 4), 256, 0, stream>>>(sums_part, cnt_part, W1,
                                                      cpb_part);
  cpb_reduce<<<NUM_CLASSES * HIDDEN / 256, 256, 0, stream>>>(cpb_part, cpb);

  // qp = q_emb @ Wq + b1  (f32 out [8192][256]), 2-phase pipeline
  gemm_qp<<<256, 256, 0, stream>>>(emb + (long)N_SUPPORT * D_EMB, WqT, b1, qp);

  // fused relation score
  score_kernel<<<N_QUERY / 32, 256, 0, stream>>>(qp, cpb, W2, b2, out);
}